// Round 6
// baseline (265.430 us; speedup 1.0000x reference)
//
#include <hip/hip_runtime.h>
#include <math.h>

#define HH 6144
#define WW 6144
constexpr int G = 50;
constexpr int NCOPY = 64;
constexpr int NG = NCOPY * G;          // 3200
constexpr int BIG = 0x0FFFFFFF;
constexpr int MINBASE = 4 * NG;        // 12800: min slots (NCOPY uints)
constexpr int CTR = MINBASE + NCOPY;   // 12864: 64 slot counters
constexpr int MASTER = CTR + NCOPY;    // 12928: master counter
constexpr int C0 = MASTER + 2;         // 12930 (even -> 8B-aligned doubles)
// const tables (word offsets from C0):
//   dT   [0,100)    tan(th)      f64 x50
//   dRC  [100,200)  rho/cos(th)  f64 x50
//   fva  [200,250)  rho/sin(tv)  f32 x50
//   fvb  [250,300)  cos/sin(tv)  f32 x50
//   dRho [300,400)  rho          f64 x50
//   dSth [400,500)  sin(th)      f64 x50
//   dCth [500,600)  cos(th)      f64 x50
//   dStv [600,700)  sin(tv)      f64 x50
//   dCtv [700,800)  cos(tv)      f64 x50

constexpr int TPB   = 512;             // 8 waves
constexpr int PXT   = 12;              // px per thread per row (48B, 16B-aligned)
constexpr int RPB   = 6;               // rows per block
constexpr int NBLK  = HH / RPB;        // 1024 blocks -> 4 blocks/CU, 32 waves/CU

// ALL global atomics relaxed — agent acq/rel on gfx950 emits L2-wide
// buffer_inv/buffer_wbl2 (per-XCD L2 non-coherent): round-4's 2.5x regression.
// Ordering: __syncthreads drains vmcnt(0) so flush atomics are globally
// performed (at the coherence point) before the counter add issues.
__device__ inline void ldsAddF(float* p, float v)      { __hip_atomic_fetch_add(p, v, __ATOMIC_RELAXED, __HIP_MEMORY_SCOPE_WORKGROUP); }
__device__ inline void ldsAddU(unsigned* p, unsigned v){ __hip_atomic_fetch_add(p, v, __ATOMIC_RELAXED, __HIP_MEMORY_SCOPE_WORKGROUP); }
__device__ inline void glbAddF(float* p, float v)      { __hip_atomic_fetch_add(p, v, __ATOMIC_RELAXED, __HIP_MEMORY_SCOPE_AGENT); }
__device__ inline void glbAddU(unsigned* p, unsigned v){ __hip_atomic_fetch_add(p, v, __ATOMIC_RELAXED, __HIP_MEMORY_SCOPE_AGENT); }
__device__ inline unsigned glbAddCtr(unsigned* p)      { return __hip_atomic_fetch_add(p, 1u, __ATOMIC_RELAXED, __HIP_MEMORY_SCOPE_AGENT); }
__device__ inline float atomLoadF(const float* p)      { return __hip_atomic_load(p, __ATOMIC_RELAXED, __HIP_MEMORY_SCOPE_AGENT); }
__device__ inline unsigned atomLoadU(const unsigned* p){ return __hip_atomic_load(p, __ATOMIC_RELAXED, __HIP_MEMORY_SCOPE_AGENT); }

// single block: zero accumulators/counters, init min slots, compute tables once
__global__ void crop_init(unsigned int* __restrict__ ws,
                          const float* __restrict__ p_rmax,
                          const float* __restrict__ p_rmin,
                          const float* __restrict__ p_thmin,
                          const float* __restrict__ p_thmax,
                          const float* __restrict__ p_tvmin,
                          const float* __restrict__ p_tvmax) {
  const int t = threadIdx.x;
  for (int i = t; i < C0; i += 256) {
    unsigned v = 0u;
    if (i >= MINBASE && i < MINBASE + NCOPY) v = 0x7F800000u;  // +inf bits
    ws[i] = v;
  }
  if (t < G) {
    double u    = (double)t / (double)(G - 1);
    double rmax = (double)p_rmax[0], rmin = (double)p_rmin[0];
    double rho  = rmax + (rmin - rmax) * u;
    double th   = (double)p_thmin[0] + ((double)p_thmax[0] - (double)p_thmin[0]) * u;
    double tv   = (double)p_tvmin[0] + ((double)p_tvmax[0] - (double)p_tvmin[0]) * u;
    double cth = cos(th), sth = sin(th);
    double ctv = cos(tv), stv = sin(tv);
    double* dT   = (double*)(ws + C0);
    double* dRC  = (double*)(ws + C0 + 100);
    float*  fva  = (float*)(ws + C0 + 200);
    float*  fvb  = (float*)(ws + C0 + 250);
    double* dRho = (double*)(ws + C0 + 300);
    double* dSth = (double*)(ws + C0 + 400);
    double* dCth = (double*)(ws + C0 + 500);
    double* dStv = (double*)(ws + C0 + 600);
    double* dCtv = (double*)(ws + C0 + 700);
    dT[t]  = tan(th);
    dRC[t] = rho / cth;
    fva[t] = (float)(rho / stv);
    fvb[t] = (float)(ctv / stv);
    dRho[t] = rho; dSth[t] = sth; dCth[t] = cth; dStv[t] = stv; dCtv[t] = ctv;
  }
}

__launch_bounds__(TPB)
__global__ void crop_main(const float* __restrict__ sp,
                          float* __restrict__ wsf,
                          float* __restrict__ out) {
  __shared__ int pxh[RPB][G], pxv[RPB][G];     // boundaries, nonincreasing in g
  __shared__ float hsum[G + 1], vsum[G + 1];   // bin G = dropped (segment id 50)
  __shared__ unsigned int hcnt[G + 1], vcnt[G + 1];
  __shared__ float wmin[TPB / 64];
  __shared__ int lastFlag;
  __shared__ double psum[100][4];
  __shared__ unsigned int pcnt[100][4];
  __shared__ float sminv;

  const int t   = threadIdx.x;
  const int bid = blockIdx.x;
  const int y0  = bid * RPB;                   // 6 contiguous rows
  const int x0  = t * PXT;

  for (int i = t; i < G + 1; i += TPB) { hsum[i] = 0.f; vsum[i] = 0.f; hcnt[i] = 0u; vcnt[i] = 0u; }

  const unsigned int* wsu = (const unsigned int*)wsf;
  // ALL 300 (row,g) boundary pairs in parallel, once per block
  if (t < RPB * G) {
    const int r = t / G, g = t - r * G;
    const int yq = min(max(y0 + r, 1), HH - 2);  // edge-effect fix == coord clamp
    const float fyq = (float)yq;
    const double* dT  = (const double*)(wsu + C0);
    const double* dRC = (const double*)(wsu + C0 + 100);
    const float*  fva = (const float*)(wsu + C0 + 200);
    const float*  fvb = (const float*)(wsu + C0 + 250);

    // horizontal family: f64 fma + half-even rint (identical to passing rounds)
    double xg = rint(fma(-(double)yq, dT[g], dRC[g]));
    xg = fmin(fmax(xg, 0.0), (double)(WW - 1));
    int xi = (int)xg;
    pxh[r][g] = (xi <= 1) ? 0 : (xi >= WW - 1 ? BIG : xi);

    // vertical family: binary-search the EXACT f32 per-pixel condition
    float va = fva[g], vb = fvb[g];
    int lo = 1, hi = WW - 1;
    while (lo < hi) {
      int m = (lo + hi) >> 1;
      float yv = rintf(fmaf(-(float)m, vb, va));
      yv = fminf(fmaxf(yv, 0.f), (float)(HH - 1));
      if (yv <= fyq) hi = m; else lo = m + 1;
    }
    pxv[r][g] = (lo >= WW - 1) ? BIG : (lo == 1 ? 0 : lo);
  }
  __syncthreads();   // the ONLY barrier before the flush

  float mn = 3.4e38f;
  const float4* rp = (const float4*)(sp + (size_t)y0 * WW) + (x0 >> 2);
  float4 c0 = rp[0], c1 = rp[1], c2 = rp[2];

  // 6 rows, no barriers: bins accumulate atomically, boundaries are read-only
  for (int r = 0; r < RPB; ++r) {
    float4 n0, n1, n2;
    if (r + 1 < RPB) {                         // prefetch next row
      const float4* np = (const float4*)(sp + (size_t)(y0 + r + 1) * WW) + (x0 >> 2);
      n0 = np[0]; n1 = np[1]; n2 = np[2];
    }

    // bin at x0: lb = first g with px*[g] <= x0 (arrays nonincreasing in g)
    int lo = 0, hi = G;
    while (lo < hi) { int m = (lo + hi) >> 1; if (pxh[r][m] <= x0) hi = m; else lo = m + 1; }
    const int lbh = lo;
    const int nbh = (lbh > 0) ? pxh[r][lbh - 1] : BIG;
    const int kh  = min(nbh - x0, PXT);        // [1,PXT]; PXT => no crossing

    lo = 0; hi = G;
    while (lo < hi) { int m = (lo + hi) >> 1; if (pxv[r][m] <= x0) hi = m; else lo = m + 1; }
    const int lbv = lo;
    const int nbv = (lbv > 0) ? pxv[r][lbv - 1] : BIG;
    const int kv  = min(nbv - x0, PXT);

    const int sh = G - lbh, sv = G - lbv;

    float px[PXT] = { c0.x,c0.y,c0.z,c0.w, c1.x,c1.y,c1.z,c1.w, c2.x,c2.y,c2.z,c2.w };
    float S = 0.f, Ah = 0.f, Av = 0.f;
#pragma unroll
    for (int k = 0; k < PXT; ++k) {
      float v = px[k];
      mn = fminf(mn, v);
      S += v;
      if (k + 1 == kh) Ah = S;
      if (k + 1 == kv) Av = S;
    }

    ldsAddF(&hsum[sh], Ah); ldsAddU(&hcnt[sh], (unsigned)kh);
    if (kh < PXT) { ldsAddF(&hsum[sh + 1], S - Ah); ldsAddU(&hcnt[sh + 1], (unsigned)(PXT - kh)); }
    ldsAddF(&vsum[sv], Av); ldsAddU(&vcnt[sv], (unsigned)kv);
    if (kv < PXT) { ldsAddF(&vsum[sv + 1], S - Av); ldsAddU(&vcnt[sv + 1], (unsigned)(PXT - kv)); }

    c0 = n0; c1 = n1; c2 = n2;
  }

  // block min reduce (8 waves)
  float m = mn;
  for (int off = 32; off; off >>= 1) m = fminf(m, __shfl_down(m, off));
  if ((t & 63) == 0) wmin[t >> 6] = m;
  __syncthreads();

  const int copy = bid & (NCOPY - 1);          // 16 blocks per copy
  unsigned int* wsw = (unsigned int*)wsf;
  if (t == 0) {
    float mm = wmin[0];
    for (int i = 1; i < TPB / 64; ++i) mm = fminf(mm, wmin[i]);
    atomicMin(&wsw[MINBASE + copy], __float_as_uint(mm));
  }
  if (t < G) {                                 // ONE flush per block (was per row)
    glbAddF(&wsf[copy * G + t], hsum[t]);
    glbAddU(&wsw[2 * NG + copy * G + t], hcnt[t]);
  } else if (t >= 64 && t < 64 + G) {
    int s = t - 64;
    glbAddF(&wsf[NG + copy * G + s], vsum[s]);
    glbAddU(&wsw[3 * NG + copy * G + s], vcnt[s]);
  }

  // ---- fused finalize: two-level relaxed done-counter ----
  __syncthreads();   // vmcnt(0) drained -> flush atomics globally performed
  if (t == 0) {
    int last = 0;
    unsigned p1 = glbAddCtr(&wsw[CTR + copy]);         // 16 blocks per slot
    if (p1 == (unsigned)(NBLK / NCOPY - 1)) {
      unsigned p2 = glbAddCtr(&wsw[MASTER]);           // 64 slot-winners
      last = (p2 == (unsigned)(NCOPY - 1));
    }
    lastFlag = last;
  }
  __syncthreads();
  if (!lastFlag) return;

  // global min over the 64 copy slots
  if (t < 64) {
    float v = __uint_as_float(atomLoadU(&wsu[MINBASE + t]));
    for (int off = 32; off; off >>= 1) v = fminf(v, __shfl_down(v, off));
    if (t == 0) sminv = v;
  }
  // 100 (fam,g) pairs x 4 chunks of 16 copies
  if (t < 400) {
    const int pair = t >> 2, chunk = t & 3;
    const int fam = pair >= G;
    const int g = fam ? pair - G : pair;
    const int sumBase = fam ? NG : 0;
    const int cntBase = (2 + fam) * NG;
    double s = 0.0; unsigned int c = 0;
#pragma unroll
    for (int i = 0; i < 16; ++i) {
      const int cp = chunk * 16 + i;
      s += (double)atomLoadF(&wsf[sumBase + cp * G + g]);
      c += atomLoadU(&wsu[cntBase + cp * G + g]);
    }
    psum[pair][chunk] = s;
    pcnt[pair][chunk] = c;
  }
  __syncthreads();

  if (t == 0) {
    const double mv = (double)sminv;
    auto val = [&](int idx) {
      double s = psum[idx][0] + psum[idx][1] + psum[idx][2] + psum[idx][3];
      double c = (double)(pcnt[idx][0] + pcnt[idx][1] + pcnt[idx][2] + pcnt[idx][3]);
      return s - mv * c;                       // scale cancels in the cumsum ratio
    };
    auto bounds = [&](int base, int& lowerI, int& upperI) {
      double tot = 0;
      for (int s = 0; s < G; ++s) tot += val(base + s);
      double c = 0; bool found = false; int last = -1; lowerI = 0;
      for (int s = 0; s < G; ++s) {
        c += val(base + s);
        double cc = c / tot;
        if (!found && cc >= 0.01) { lowerI = s; found = true; }
        if (cc <= 0.99) last = s;
      }
      upperI = (last < 0) ? (G + 1) : (last + 2);  // all-false reversed argmax -> 51
    };
    int lh, uh, lv, uv;
    bounds(0, lh, uh);
    bounds(G, lv, uv);

    const double* dRho = (const double*)(wsu + C0 + 300);
    const double* dSth = (const double*)(wsu + C0 + 400);
    const double* dCth = (const double*)(wsu + C0 + 500);
    const double* dStv = (const double*)(wsu + C0 + 600);
    const double* dCtv = (const double*)(wsu + C0 + 700);

    auto tn = [&](int i) { return ((G - i) % G + G) % G; };  // python a[-i]
    int ihmin = tn(lh), ihmax = tn(uh), ivmin = tn(lv), ivmax = tn(uv);

    auto inter = [&](int ih, int iv, float* o) {
      double r1 = dRho[ih], s1 = dSth[ih], c1 = dCth[ih];
      double r2 = dRho[iv], s2 = dStv[iv], c2 = dCtv[iv];
      double det = c1 * s2 - c2 * s1;
      o[0] = (float)((r1 * s2 - r2 * s1) / det);
      o[1] = (float)((r2 * c1 - r1 * c2) / det);
    };
    inter(ihmin, ivmin, out + 0);
    inter(ihmax, ivmin, out + 2);
    inter(ihmax, ivmax, out + 4);
    inter(ihmin, ivmax, out + 6);
  }
}

extern "C" void kernel_launch(void* const* d_in, const int* in_sizes, int n_in,
                              void* d_out, int out_size, void* d_ws, size_t ws_size,
                              hipStream_t stream) {
  const float* sp    = (const float*)d_in[0];
  const float* rmax  = (const float*)d_in[1];
  const float* rmin  = (const float*)d_in[2];
  const float* thmin = (const float*)d_in[3];
  const float* thmax = (const float*)d_in[4];
  const float* tvmin = (const float*)d_in[5];
  const float* tvmax = (const float*)d_in[6];
  float* wsf  = (float*)d_ws;
  float* outp = (float*)d_out;

  crop_init<<<1, 256, 0, stream>>>((unsigned int*)d_ws,
                                   rmax, rmin, thmin, thmax, tvmin, tvmax);
  crop_main<<<NBLK, TPB, 0, stream>>>(sp, wsf, outp);
}

// Round 7
// 251.603 us; speedup vs baseline: 1.0550x; 1.0550x over previous
//
#include <hip/hip_runtime.h>
#include <math.h>

#define HH 6144
#define WW 6144
constexpr int G = 50;
constexpr int NCOPY = 64;
constexpr int NG = NCOPY * G;          // 3200
constexpr int BIG = 0x0FFFFFFF;
constexpr int MINBASE = 4 * NG;        // 12800: min slots (NCOPY uints)
constexpr int CTR = MINBASE + NCOPY;   // 12864: 64 slot counters
constexpr int MASTER = CTR + NCOPY;    // 12928: master counter
constexpr int C0 = MASTER + 2;         // 12930 (even -> 8B-aligned doubles)
// const tables (word offsets from C0):
//   dT   [0,100)    tan(th)      f64 x50
//   dRC  [100,200)  rho/cos(th)  f64 x50
//   fva  [200,250)  rho/sin(tv)  f32 x50
//   fvb  [250,300)  cos/sin(tv)  f32 x50
//   dRho [300,400)  rho          f64 x50
//   dSth [400,500)  sin(th)      f64 x50
//   dCth [500,600)  cos(th)      f64 x50
//   dStv [600,700)  sin(tv)      f64 x50
//   dCtv [700,800)  cos(tv)      f64 x50

constexpr int TPB  = 384;              // 6 waves
constexpr int PXT  = 16;               // px per thread
constexpr int NBLK = HH;               // 1 row per block; 96 blocks per copy slot

// ALL global atomics relaxed — agent acq/rel on gfx950 emits L2-wide
// buffer_inv/buffer_wbl2 (per-XCD L2 non-coherent): round-4's 2.5x regression.
// Flush->counter ordering: wave-0-local s_waitcnt vmcnt(0) (all flush atomics
// are issued by wave 0), NOT a block barrier — waves 1..5 retire early so the
// ~3 dependent fabric round trips sit on 1 wave instead of 6 (round-6 lesson).
__device__ inline void ldsAddF(float* p, float v)      { __hip_atomic_fetch_add(p, v, __ATOMIC_RELAXED, __HIP_MEMORY_SCOPE_WORKGROUP); }
__device__ inline void ldsAddU(unsigned* p, unsigned v){ __hip_atomic_fetch_add(p, v, __ATOMIC_RELAXED, __HIP_MEMORY_SCOPE_WORKGROUP); }
__device__ inline void ldsMinU(unsigned* p, unsigned v){ __hip_atomic_fetch_min(p, v, __ATOMIC_RELAXED, __HIP_MEMORY_SCOPE_WORKGROUP); }
__device__ inline void glbAddF(float* p, float v)      { __hip_atomic_fetch_add(p, v, __ATOMIC_RELAXED, __HIP_MEMORY_SCOPE_AGENT); }
__device__ inline void glbAddU(unsigned* p, unsigned v){ __hip_atomic_fetch_add(p, v, __ATOMIC_RELAXED, __HIP_MEMORY_SCOPE_AGENT); }
__device__ inline void glbMinU(unsigned* p, unsigned v){ __hip_atomic_fetch_min(p, v, __ATOMIC_RELAXED, __HIP_MEMORY_SCOPE_AGENT); }
__device__ inline unsigned glbAddCtr(unsigned* p)      { return __hip_atomic_fetch_add(p, 1u, __ATOMIC_RELAXED, __HIP_MEMORY_SCOPE_AGENT); }
__device__ inline float atomLoadF(const float* p)      { return __hip_atomic_load(p, __ATOMIC_RELAXED, __HIP_MEMORY_SCOPE_AGENT); }
__device__ inline unsigned atomLoadU(const unsigned* p){ return __hip_atomic_load(p, __ATOMIC_RELAXED, __HIP_MEMORY_SCOPE_AGENT); }

__global__ void crop_init(unsigned int* __restrict__ ws,
                          const float* __restrict__ p_rmax,
                          const float* __restrict__ p_rmin,
                          const float* __restrict__ p_thmin,
                          const float* __restrict__ p_thmax,
                          const float* __restrict__ p_tvmin,
                          const float* __restrict__ p_tvmax) {
  int i = blockIdx.x * 256 + threadIdx.x;
  if (i < MINBASE) ws[i] = 0u;
  else if (i < MINBASE + NCOPY) ws[i] = 0x7F800000u;   // +inf bits
  else if (i < C0) ws[i] = 0u;                         // counters + pad

  if (blockIdx.x == 0 && threadIdx.x < G) {
    int t = threadIdx.x;
    double u    = (double)t / (double)(G - 1);
    double rmax = (double)p_rmax[0], rmin = (double)p_rmin[0];
    double rho  = rmax + (rmin - rmax) * u;
    double th   = (double)p_thmin[0] + ((double)p_thmax[0] - (double)p_thmin[0]) * u;
    double tv   = (double)p_tvmin[0] + ((double)p_tvmax[0] - (double)p_tvmin[0]) * u;
    double cth = cos(th), sth = sin(th);
    double ctv = cos(tv), stv = sin(tv);
    double* dT   = (double*)(ws + C0);
    double* dRC  = (double*)(ws + C0 + 100);
    float*  fva  = (float*)(ws + C0 + 200);
    float*  fvb  = (float*)(ws + C0 + 250);
    double* dRho = (double*)(ws + C0 + 300);
    double* dSth = (double*)(ws + C0 + 400);
    double* dCth = (double*)(ws + C0 + 500);
    double* dStv = (double*)(ws + C0 + 600);
    double* dCtv = (double*)(ws + C0 + 700);
    dT[t]  = tan(th);
    dRC[t] = rho / cth;
    fva[t] = (float)(rho / stv);
    fvb[t] = (float)(ctv / stv);
    dRho[t] = rho; dSth[t] = sth; dCth[t] = cth; dStv[t] = stv; dCtv[t] = ctv;
  }
}

__launch_bounds__(TPB)
__global__ void crop_main(const float* __restrict__ sp,
                          float* __restrict__ wsf,
                          float* __restrict__ out) {
  __shared__ int pxh[G], pxv[G];               // boundaries, nonincreasing in g
  __shared__ float hsum[G + 1], vsum[G + 1];   // bin G = dropped (segment id 50)
  __shared__ unsigned int hcnt[G + 1], vcnt[G + 1];
  __shared__ unsigned int blockMinBits;        // sp >= 0: uint order == float order
  __shared__ double valD[100];                 // last-block finalize scratch

  const int t  = threadIdx.x;
  const int y  = blockIdx.x;
  const int yp = min(max(y, 1), HH - 2);       // edge-effect fix == coord clamp
  const float fyp = (float)yp;
  const int x0 = t * PXT;

  // issue pixel loads first (latency overlaps setup)
  const float4* p4 = (const float4*)(sp + (size_t)y * WW + x0);
  float4 q0 = p4[0], q1 = p4[1], q2 = p4[2], q3 = p4[3];

  for (int i = t; i < G + 1; i += TPB) { hsum[i] = 0.f; vsum[i] = 0.f; hcnt[i] = 0u; vcnt[i] = 0u; }
  if (t == TPB - 1) blockMinBits = 0x7F800000u;

  const unsigned int* wsu = (const unsigned int*)wsf;
  if (t < G) {
    const double* dT  = (const double*)(wsu + C0);
    const double* dRC = (const double*)(wsu + C0 + 100);
    const float*  fva = (const float*)(wsu + C0 + 200);
    const float*  fvb = (const float*)(wsu + C0 + 250);

    // horizontal family: f64 fma + half-even rint (identical to passing rounds)
    double xg = rint(fma(-(double)yp, dT[t], dRC[t]));
    xg = fmin(fmax(xg, 0.0), (double)(WW - 1));
    int xi = (int)xg;
    pxh[t] = (xi <= 1) ? 0 : (xi >= WW - 1 ? BIG : xi);

    // vertical family: binary-search the EXACT f32 per-pixel condition
    float va = fva[t], vb = fvb[t];
    int lo = 1, hi = WW - 1;
    while (lo < hi) {
      int m = (lo + hi) >> 1;
      float yv = rintf(fmaf(-(float)m, vb, va));
      yv = fminf(fmaxf(yv, 0.f), (float)(HH - 1));
      if (yv <= fyp) hi = m; else lo = m + 1;
    }
    pxv[t] = (lo >= WW - 1) ? BIG : (lo == 1 ? 0 : lo);
  }
  __syncthreads();                             // barrier #1

  float px[PXT] = { q0.x,q0.y,q0.z,q0.w, q1.x,q1.y,q1.z,q1.w,
                    q2.x,q2.y,q2.z,q2.w, q3.x,q3.y,q3.z,q3.w };

  // bin at x0: lb = first g with px*[g] <= x0 (arrays nonincreasing in g)
  int lo = 0, hi = G;
  while (lo < hi) { int m = (lo + hi) >> 1; if (pxh[m] <= x0) hi = m; else lo = m + 1; }
  const int lbh = lo;
  const int nbh = (lbh > 0) ? pxh[lbh - 1] : BIG;
  const int kh  = min(nbh - x0, PXT);          // [1,PXT]; PXT => no crossing in run

  lo = 0; hi = G;
  while (lo < hi) { int m = (lo + hi) >> 1; if (pxv[m] <= x0) hi = m; else lo = m + 1; }
  const int lbv = lo;
  const int nbv = (lbv > 0) ? pxv[lbv - 1] : BIG;
  const int kv  = min(nbv - x0, PXT);

  const int sh = G - lbh, sv = G - lbv;

  float S = 0.f, Ah = 0.f, Av = 0.f, mn = 3.4e38f;
#pragma unroll
  for (int k = 0; k < PXT; ++k) {
    float v = px[k];
    mn = fminf(mn, v);
    S += v;
    if (k + 1 == kh) Ah = S;
    if (k + 1 == kv) Av = S;
  }

  ldsAddF(&hsum[sh], Ah); ldsAddU(&hcnt[sh], (unsigned)kh);
  if (kh < PXT) { ldsAddF(&hsum[sh + 1], S - Ah); ldsAddU(&hcnt[sh + 1], (unsigned)(PXT - kh)); }
  ldsAddF(&vsum[sv], Av); ldsAddU(&vcnt[sv], (unsigned)kv);
  if (kv < PXT) { ldsAddF(&vsum[sv + 1], S - Av); ldsAddU(&vcnt[sv + 1], (unsigned)(PXT - kv)); }

  // per-wave min -> one LDS atomicMin per wave (no extra barrier/LDS array)
  for (int off = 32; off; off >>= 1) mn = fminf(mn, __shfl_down(mn, off));
  if ((t & 63) == 0) ldsMinU(&blockMinBits, __float_as_uint(mn));

  __syncthreads();                             // barrier #2: bins + min complete

  if (t >= 64) return;                         // waves 1..5 free their slots NOW

  // ---- wave 0 only: global flush + counter cascade ----
  const int copy = y & (NCOPY - 1);
  unsigned int* wsw = (unsigned int*)wsf;
  if (t < G) {                                 // 4 atomics per lane, one wave
    glbAddF(&wsf[copy * G + t], hsum[t]);
    glbAddU(&wsw[2 * NG + copy * G + t], hcnt[t]);
    glbAddF(&wsf[NG + copy * G + t], vsum[t]);
    glbAddU(&wsw[3 * NG + copy * G + t], vcnt[t]);
  }
  if (t == 0) glbMinU(&wsw[MINBASE + copy], blockMinBits);

  // order: this wave's flush atomics globally performed before counter add
  asm volatile("s_waitcnt vmcnt(0)" ::: "memory");

  int last = 0;
  if (t == 0) {
    unsigned p1 = glbAddCtr(&wsw[CTR + copy]);          // 96 blocks per slot
    if (p1 == (unsigned)(NBLK / NCOPY - 1)) {
      unsigned p2 = glbAddCtr(&wsw[MASTER]);            // 64 slot-winners
      last = (p2 == (unsigned)(NCOPY - 1));
    }
  }
  last = __shfl(last, 0);
  if (!last) return;

  // ---- last block, 64-lane finalize ----
  float vmn = __uint_as_float(atomLoadU(&wsu[MINBASE + t]));
  for (int off = 32; off; off >>= 1) vmn = fminf(vmn, __shfl_down(vmn, off));
  const double mv = (double)__shfl(vmn, 0);

  for (int p = t; p < 100; p += 64) {
    const int fam = p >= G;
    const int g = fam ? p - G : p;
    const int sumBase = fam ? NG : 0;
    const int cntBase = (2 + fam) * NG;
    double s = 0.0; unsigned c = 0;
#pragma unroll 8
    for (int cp = 0; cp < NCOPY; ++cp) {
      s += (double)atomLoadF(&wsf[sumBase + cp * G + g]);
      c += atomLoadU(&wsu[cntBase + cp * G + g]);
    }
    valD[p] = s - mv * (double)c;              // scale cancels in the cumsum ratio
  }
  // fence: lanes' LDS writes complete before lane 0 reads (rule #18 pattern)
  asm volatile("s_waitcnt lgkmcnt(0)" ::: "memory");
  __builtin_amdgcn_sched_barrier(0);

  if (t == 0) {
    auto bounds = [&](int base, int& lowerI, int& upperI) {
      double tot = 0;
      for (int s = 0; s < G; ++s) tot += valD[base + s];
      double c = 0; bool found = false; int lastI = -1; lowerI = 0;
      for (int s = 0; s < G; ++s) {
        c += valD[base + s];
        double cc = c / tot;
        if (!found && cc >= 0.01) { lowerI = s; found = true; }
        if (cc <= 0.99) lastI = s;
      }
      upperI = (lastI < 0) ? (G + 1) : (lastI + 2);  // all-false reversed argmax -> 51
    };
    int lh, uh, lv, uv;
    bounds(0, lh, uh);
    bounds(G, lv, uv);

    const double* dRho = (const double*)(wsu + C0 + 300);
    const double* dSth = (const double*)(wsu + C0 + 400);
    const double* dCth = (const double*)(wsu + C0 + 500);
    const double* dStv = (const double*)(wsu + C0 + 600);
    const double* dCtv = (const double*)(wsu + C0 + 700);

    auto tn = [&](int i) { return ((G - i) % G + G) % G; };  // python a[-i]
    int ihmin = tn(lh), ihmax = tn(uh), ivmin = tn(lv), ivmax = tn(uv);

    auto inter = [&](int ih, int iv, float* o) {
      double r1 = dRho[ih], s1 = dSth[ih], c1 = dCth[ih];
      double r2 = dRho[iv], s2 = dStv[iv], c2 = dCtv[iv];
      double det = c1 * s2 - c2 * s1;
      o[0] = (float)((r1 * s2 - r2 * s1) / det);
      o[1] = (float)((r2 * c1 - r1 * c2) / det);
    };
    inter(ihmin, ivmin, out + 0);
    inter(ihmax, ivmin, out + 2);
    inter(ihmax, ivmax, out + 4);
    inter(ihmin, ivmax, out + 6);
  }
}

extern "C" void kernel_launch(void* const* d_in, const int* in_sizes, int n_in,
                              void* d_out, int out_size, void* d_ws, size_t ws_size,
                              hipStream_t stream) {
  const float* sp    = (const float*)d_in[0];
  const float* rmax  = (const float*)d_in[1];
  const float* rmin  = (const float*)d_in[2];
  const float* thmin = (const float*)d_in[3];
  const float* thmax = (const float*)d_in[4];
  const float* tvmin = (const float*)d_in[5];
  const float* tvmax = (const float*)d_in[6];
  float* wsf  = (float*)d_ws;
  float* outp = (float*)d_out;

  crop_init<<<(C0 + 255) / 256, 256, 0, stream>>>((unsigned int*)d_ws,
                                                  rmax, rmin, thmin, thmax, tvmin, tvmax);
  crop_main<<<NBLK, TPB, 0, stream>>>(sp, wsf, outp);
}